// Round 4
// baseline (22.393 us; speedup 1.0000x reference)
//
#include <hip/hip_runtime.h>
#include <hip/hip_bf16.h>

// Segment-mean over sorted indexes — single dispatch, row-slab load balancing.
// hidden: [B=8, S=2048, D=768] f32; ori_indexes: [B, S] sorted int (<T=1024)
// out:    [B, T, D] f32 = segment_sum / clip(count,1)
//
// Wave g (of 1024 per batch) owns rows {2g, 2g+1}. A token whose FIRST row
// falls in that window is summed entirely by this wave (scan forward to the
// token's end). Each hidden row is therefore read by exactly one wave, and
// each CU's read workload is exactly its contiguous 64-row slab -> per-CU
// load variance ~0 (vs ±36% tail with per-token assignment).
// Empty tokens (no rows) are zero-written by wave g for token t=g, detected
// via two uniform L1-resident binary searches. Every output row is written
// exactly once; fully deterministic; no workspace.

#define SGA_B 8
#define SGA_S 2048
#define SGA_D 768
#define SGA_T 1024
#define SGA_NV (SGA_D / 4)   // 192 float4 per row

typedef float f32x4 __attribute__((ext_vector_type(4)));

__global__ __launch_bounds__(256) void sga_segmean_kernel(
    const float* __restrict__ hidden,
    const int* __restrict__ idx,
    float* __restrict__ out) {
    const int b = blockIdx.y;
    const int w = blockIdx.x * 4 + (threadIdx.x >> 6);  // wave id, 0..1023
    const int lane = threadIdx.x & 63;

    const int* __restrict__ ib = idx + b * SGA_S;

    const f32x4* __restrict__ hbase =
        reinterpret_cast<const f32x4*>(hidden) + (size_t)b * SGA_S * SGA_NV + lane;
    f32x4* __restrict__ obat =
        reinterpret_cast<f32x4*>(out) + (size_t)b * SGA_T * SGA_NV + lane;

    // --- (a) empty-token check for t = w (wave-uniform binary searches) ---
    int lo = 0, hi = SGA_S;
    while (lo < hi) { int m = (lo + hi) >> 1; if (ib[m] < w) lo = m + 1; else hi = m; }
    const int s0 = lo;
    hi = SGA_S;
    while (lo < hi) { int m = (lo + hi) >> 1; if (ib[m] < w + 1) lo = m + 1; else hi = m; }
    if (s0 == lo) {  // token w has no rows -> reference outputs zeros
        f32x4 z = (f32x4)0.f;
        f32x4* o = obat + (size_t)w * SGA_NV;
        __builtin_nontemporal_store(z, o);
        __builtin_nontemporal_store(z, o + 64);
        __builtin_nontemporal_store(z, o + 128);
    }

    // --- (b) tokens starting in row window {2w, 2w+1} ---
    const int r0 = 2 * w;
#pragma unroll
    for (int rr = r0; rr < r0 + 2; ++rr) {
        const int t = ib[rr];
        const int p = (rr == 0) ? -1 : ib[rr - 1];
        if (t != p) {  // token t starts at row rr
            int e = rr + 1;
            while (e < SGA_S && ib[e] == t) ++e;

            f32x4 a0 = (f32x4)0.f, a1 = (f32x4)0.f, a2 = (f32x4)0.f;
            int s = rr;
            for (; s + 1 < e; s += 2) {
                const f32x4* r0p = hbase + (size_t)s * SGA_NV;
                const f32x4* r1p = r0p + SGA_NV;
                f32x4 v00 = __builtin_nontemporal_load(r0p);
                f32x4 v01 = __builtin_nontemporal_load(r0p + 64);
                f32x4 v02 = __builtin_nontemporal_load(r0p + 128);
                f32x4 v10 = __builtin_nontemporal_load(r1p);
                f32x4 v11 = __builtin_nontemporal_load(r1p + 64);
                f32x4 v12 = __builtin_nontemporal_load(r1p + 128);
                a0 += v00; a1 += v01; a2 += v02;
                a0 += v10; a1 += v11; a2 += v12;
            }
            if (s < e) {
                const f32x4* rp = hbase + (size_t)s * SGA_NV;
                a0 += __builtin_nontemporal_load(rp);
                a1 += __builtin_nontemporal_load(rp + 64);
                a2 += __builtin_nontemporal_load(rp + 128);
            }

            const float inv = 1.0f / (float)(e - rr);
            a0 *= inv; a1 *= inv; a2 *= inv;

            f32x4* o = obat + (size_t)t * SGA_NV;
            __builtin_nontemporal_store(a0, o);
            __builtin_nontemporal_store(a1, o + 64);
            __builtin_nontemporal_store(a2, o + 128);
        }
    }
}

extern "C" void kernel_launch(void* const* d_in, const int* in_sizes, int n_in,
                              void* d_out, int out_size, void* d_ws, size_t ws_size,
                              hipStream_t stream) {
    const float* hidden = (const float*)d_in[0];
    const int* idx = (const int*)d_in[1];
    float* out = (float*)d_out;

    dim3 grid(SGA_T / 4, SGA_B, 1);   // 2048 blocks x 256 threads (4 waves)
    sga_segmean_kernel<<<grid, dim3(256, 1, 1), 0, stream>>>(hidden, idx, out);
}